// Round 10
// baseline (8541.996 us; speedup 1.0000x reference)
//
#include <hip/hip_runtime.h>
#include <cstdint>

// Reference semantics (validated, absmax=0.0 — DO NOT change arithmetic):
//  - selection on RAW f32 coords, distance = fma(dz,dz, fma(dx,dx, dy*dy))
//    with dx/dy/dz plain f32 subs;
//  - min/argmax exact, FIRST-index tie-break (min global point index);
//  - output coords bf16-RNE-rounded, batch = float b.
//
// R21: R20 (packed/stride-17) regressed -> reverted. Unified VGPR theory:
// the backend sets the VGPR budget from LDS-implied max occupancy and
// ignores waves_per_eu. Tiny-LDS rounds (R12/R15/R16) got budget 64 ->
// remat/spill of point coords. R19 (131KB LDS) got budget 128 and kept its
// 32 regs resident. So: keep a BIG LDS (120.8KB, 1 block/CU, budget 128)
// and put ALL coords in registers: px,py,pz,m x16 = 64 regs + ~25 temps
// ~= 90 < 128. UPD is pure VALU (7 instr/pt, ZERO loop ds_reads) -- kills
// the per-iter 256-instr DS burst and its barrier-skew spread.
// Center broadcast: each wave publishes its winner's coords (uniform-slot
// select + 3 readlane) as a 16B Cand record beside the key; finalize reads
// key+cand in one overlapped LDS round-trip and takes the block center via
// 3 readlanes -- no post-finalize LDS read, no global cz. All bit-copies;
// reduce lattice unchanged from R19 (validated).
#pragma clang fp contract(off)

#define B_ 16
#define N_ 16384
#define K_ 4096
#define THREADS_ 1024
#define NW_ (THREADS_ / 64)    // 16 waves per block

#define PTS_LIST(X) \
  X(0) X(1) X(2) X(3) X(4) X(5) X(6) X(7) \
  X(8) X(9) X(10) X(11) X(12) X(13) X(14) X(15)

// f32 -> bf16 RNE, returned as the bf16-representable f32 (finite inputs)
__device__ __forceinline__ float bfr(float f) {
  union { float f; uint32_t i; } c; c.f = f;
  c.i = (c.i + 0x7FFFu + ((c.i >> 16) & 1u)) & 0xFFFF0000u;
  return c.f;
}

// ---- DPP helpers (ctrl is a template constant) -----------------------------
template <int CTRL>
__device__ __forceinline__ float dpp_fmax(float v) {
  union { float f; int i; } s, p;
  s.f = v;
  p.i = __builtin_amdgcn_update_dpp(0, s.i, CTRL, 0xF, 0xF, false);
  return fmaxf(v, p.f);
}
template <int CTRL>
__device__ __forceinline__ unsigned dpp_umin(unsigned v) {
  const int p = __builtin_amdgcn_update_dpp((int)0xFFFFFFFFu, (int)v,
                                            CTRL, 0xF, 0xF, false);
  const unsigned pu = (unsigned)p;
  return pu < v ? pu : v;
}

// wave-wide (max bv, min bg among maxed) -> (wv, wg), uniform in all lanes.
__device__ __forceinline__ void wave_argmax(float bv, unsigned bg,
                                            float& wv, unsigned& wg) {
  float v = bv;
  v = dpp_fmax<0x111>(v);  // row_shr:1
  v = dpp_fmax<0x112>(v);  // row_shr:2
  v = dpp_fmax<0x114>(v);  // row_shr:4
  v = dpp_fmax<0x118>(v);  // row_shr:8
  v = dpp_fmax<0x142>(v);  // row_bcast:15
  v = dpp_fmax<0x143>(v);  // row_bcast:31
  union { float f; int i; } mx;
  mx.i = __builtin_amdgcn_readlane(__builtin_bit_cast(int, v), 63);
  unsigned c = (bv == mx.f) ? bg : 0xFFFFFFFFu;
  c = dpp_umin<0x111>(c);
  c = dpp_umin<0x112>(c);
  c = dpp_umin<0x114>(c);
  c = dpp_umin<0x118>(c);
  c = dpp_umin<0x142>(c);
  c = dpp_umin<0x143>(c);
  wg = (unsigned)__builtin_amdgcn_readlane((int)c, 63);
  wv = mx.f;
}

// u64 key max over a DPP lane-permutation (block-finalize butterfly; key is
// (f32bits(dist)<<32)|~idx so u64 max == (max dist, min index)). Exact.
template <int CTRL>
__device__ __forceinline__ unsigned long long kmax_dpp(unsigned long long k) {
  const int lo = (int)(unsigned)k;
  const int hi = (int)(unsigned)(k >> 32);
  const int plo = __builtin_amdgcn_update_dpp(lo, lo, CTRL, 0xF, 0xF, true);
  const int phi = __builtin_amdgcn_update_dpp(hi, hi, CTRL, 0xF, 0xF, true);
  const unsigned long long ok =
      ((unsigned long long)(unsigned)phi << 32) | (unsigned)plo;
  return ok > k ? ok : k;
}

struct alignas(16) Cand { float cx, cy, cz, pad; };

__global__ __attribute__((amdgpu_flat_work_group_size(THREADS_, THREADS_),
                          amdgpu_waves_per_eu(4, 4)))
void fps_kernel(const float* __restrict__ x, float* __restrict__ out)
{
#pragma clang fp contract(off)
  const int b    = blockIdx.x;
  const int t    = threadIdx.x;
  const int lane = t & 63;
  const int wave = t >> 6;

  // Oversized ON PURPOSE: 120.8 KB total forces 1 block/CU, which sets the
  // backend's occupancy target to 4 waves/EU and the VGPR budget to 128 —
  // that is what lets the 64 coordinate registers below stay resident.
  // Only [parity][wave<16] entries are ever touched.
  __shared__ unsigned long long s_key[2][3200];   // 51.2 KB
  __shared__ Cand               s_cand[2][2176];  // 69.6 KB

  const float* xb  = x + (size_t)b * (N_ * 3);
  float* out_x     = out;                        // [B*K*3] f32 (bf16-grid values)
  float* out_batch = out + (size_t)B_ * K_ * 3;  // [B*K]   f32 cloud ids

  // batch output (buffer re-poisoned every call -> rewrite every call)
  {
    const float bb = (float)b;
    for (int i = t; i < K_; i += THREADS_) out_batch[b * K_ + i] = bb;
  }

  // ALL point state in named registers; slot i owns point i*1024 + t
#define DECLP(i) float px##i, py##i, pz##i, m##i;
  PTS_LIST(DECLP)
#undef DECLP

#define LOADP(i) { const float* p_ = xb + 3 * ((i) * THREADS_ + t); \
                   px##i = p_[0]; py##i = p_[1]; pz##i = p_[2];     \
                   m##i = __builtin_inff(); }
  PTS_LIST(LOADP)
#undef LOADP

  // dist update (bit-exact FMA-V1), min into m##i — pure VALU, no memory
#define UPD(i) { const float dx_ = px##i - cx;                                  \
                 const float dy_ = py##i - cy;                                  \
                 const float dz_ = pz##i - cz;                                  \
                 const float d_  = __builtin_fmaf(dz_, dz_,                     \
                                   __builtin_fmaf(dx_, dx_, dy_ * dy_));        \
                 m##i = fminf(m##i, d_); }

  // max3 tree over the 16 m values; value identical to sequential max.
#define MAXTREE(M_) { const float t0_ = fmaxf(fmaxf(m0,  m1),  m2);  \
                      const float t1_ = fmaxf(fmaxf(m3,  m4),  m5);  \
                      const float t2_ = fmaxf(fmaxf(m6,  m7),  m8);  \
                      const float t3_ = fmaxf(fmaxf(m9,  m10), m11); \
                      const float t4_ = fmaxf(fmaxf(m12, m13), m14); \
                      const float u0_ = fmaxf(fmaxf(t0_, t1_), t2_); \
                      const float u1_ = fmaxf(fmaxf(t3_, t4_), m15); \
                      M_ = fmaxf(u0_, u1_); }

  // descending equality chain: final bs = smallest slot with m==M
#define IDXCHAIN(M_, BS_) { BS_ = 15;                                \
      if (m14 == M_) BS_ = 14; if (m13 == M_) BS_ = 13;              \
      if (m12 == M_) BS_ = 12; if (m11 == M_) BS_ = 11;              \
      if (m10 == M_) BS_ = 10; if (m9  == M_) BS_ = 9;               \
      if (m8  == M_) BS_ = 8;  if (m7  == M_) BS_ = 7;               \
      if (m6  == M_) BS_ = 6;  if (m5  == M_) BS_ = 5;               \
      if (m4  == M_) BS_ = 4;  if (m3  == M_) BS_ = 3;               \
      if (m2  == M_) BS_ = 2;  if (m1  == M_) BS_ = 1;               \
      if (m0  == M_) BS_ = 0; }

  // per-thread argmax -> wave argmax -> publish key + winner coords.
  // Winner of this wave is owned by a lane IN this wave (g = bs*1024+t:
  // owner lane = wg&63, owner slot = wg>>10, both wave-uniform). All lanes
  // run the uniform-slot select (scalar branches); owner's values are then
  // broadcast with readlane. Pure bit-copies of the originally loaded f32.
#define REDUCE_AND_POST(P) {                                             \
      float bv; int bs;                                                  \
      MAXTREE(bv)                                                        \
      IDXCHAIN(bv, bs)                                                   \
      const unsigned bg = (unsigned)(bs * THREADS_ + t);                 \
      float wv; unsigned wg;                                             \
      wave_argmax(bv, bg, wv, wg);                                       \
      const unsigned wgu = (unsigned)__builtin_amdgcn_readfirstlane((int)wg); \
      const unsigned su  = wgu >> 10;                                    \
      float sx = px0, sy = py0, sz = pz0;                                \
      if (su == 1)  { sx = px1;  sy = py1;  sz = pz1;  }                 \
      if (su == 2)  { sx = px2;  sy = py2;  sz = pz2;  }                 \
      if (su == 3)  { sx = px3;  sy = py3;  sz = pz3;  }                 \
      if (su == 4)  { sx = px4;  sy = py4;  sz = pz4;  }                 \
      if (su == 5)  { sx = px5;  sy = py5;  sz = pz5;  }                 \
      if (su == 6)  { sx = px6;  sy = py6;  sz = pz6;  }                 \
      if (su == 7)  { sx = px7;  sy = py7;  sz = pz7;  }                 \
      if (su == 8)  { sx = px8;  sy = py8;  sz = pz8;  }                 \
      if (su == 9)  { sx = px9;  sy = py9;  sz = pz9;  }                 \
      if (su == 10) { sx = px10; sy = py10; sz = pz10; }                 \
      if (su == 11) { sx = px11; sy = py11; sz = pz11; }                 \
      if (su == 12) { sx = px12; sy = py12; sz = pz12; }                 \
      if (su == 13) { sx = px13; sy = py13; sz = pz13; }                 \
      if (su == 14) { sx = px14; sy = py14; sz = pz14; }                 \
      if (su == 15) { sx = px15; sy = py15; sz = pz15; }                 \
      const int ol_ = (int)(wgu & 63u);                                  \
      const int cxi = __builtin_amdgcn_readlane(__builtin_bit_cast(int, sx), ol_); \
      const int cyi = __builtin_amdgcn_readlane(__builtin_bit_cast(int, sy), ol_); \
      const int czi = __builtin_amdgcn_readlane(__builtin_bit_cast(int, sz), ol_); \
      if (lane == 0) {                                                   \
        union { float f; unsigned u; } cv; cv.f = wv;                    \
        s_key[P][wave] =                                                 \
            ((unsigned long long)cv.u << 32) | (unsigned)~wgu;           \
        Cand c_;                                                         \
        c_.cx = __builtin_bit_cast(float, cxi);                          \
        c_.cy = __builtin_bit_cast(float, cyi);                          \
        c_.cz = __builtin_bit_cast(float, czi);                          \
        c_.pad = 0.0f;                                                   \
        s_cand[P][wave] = c_;                                            \
      } }

  // ---- iteration 0: seed = point 0 ----
  float cx = xb[0], cy = xb[1], cz = xb[2];
  if (t == 0) {
    const uint64_t o = ((uint64_t)b * K_) * 3;
    out_x[o + 0] = bfr(cx); out_x[o + 1] = bfr(cy); out_x[o + 2] = bfr(cz);
  }

  PTS_LIST(UPD)                      // m_i = d_i (min with +inf)
  REDUCE_AND_POST(0)
  __syncthreads();

  // ---- iterations 1..K-1 ----
  for (int j = 1; j < K_; ++j) {
    const int rp = (j - 1) & 1;
    const int wp = j & 1;

    // finalize block argmax: lanes grab key+cand of wave (lane&15) in one
    // overlapped LDS round-trip; 4 DPP levels within each 16-lane row ->
    // every lane holds the block winner; center via 3 readlanes.
    unsigned long long k = s_key[rp][lane & 15];
    const Cand cd = s_cand[rp][lane & 15];
    k = kmax_dpp<0xB1>(k);    // quad_perm lane^1
    k = kmax_dpp<0x4E>(k);    // quad_perm lane^2
    k = kmax_dpp<0x141>(k);   // row_half_mirror (lane^7, covers ^4)
    k = kmax_dpp<0x140>(k);   // row_mirror (lane^15, covers ^8)
    const unsigned g = ~(unsigned)k;             // winner global point index
    const int gu = __builtin_amdgcn_readfirstlane((int)g);
    const int ws = (gu >> 6) & 15;               // winner wave id
    cx = __builtin_bit_cast(float,
           __builtin_amdgcn_readlane(__builtin_bit_cast(int, cd.cx), ws));
    cy = __builtin_bit_cast(float,
           __builtin_amdgcn_readlane(__builtin_bit_cast(int, cd.cy), ws));
    cz = __builtin_bit_cast(float,
           __builtin_amdgcn_readlane(__builtin_bit_cast(int, cd.cz), ws));
    if (t == 0) {
      const uint64_t o = ((uint64_t)b * K_ + j) * 3;
      out_x[o + 0] = bfr(cx); out_x[o + 1] = bfr(cy); out_x[o + 2] = bfr(cz);
    }

    // pure-VALU update + reduce/publish for next round
    PTS_LIST(UPD)
    REDUCE_AND_POST(wp)
    __syncthreads();
  }
#undef UPD
#undef MAXTREE
#undef IDXCHAIN
#undef REDUCE_AND_POST

}

extern "C" void kernel_launch(void* const* d_in, const int* in_sizes, int n_in,
                              void* d_out, int out_size, void* d_ws, size_t ws_size,
                              hipStream_t stream) {
  const float* x = (const float*)d_in[0];  // f32, [B*N, 3]
  float* out     = (float*)d_out;          // f32: [B*K*3] coords + [B*K] batch
  (void)in_sizes; (void)n_in; (void)out_size; (void)d_ws; (void)ws_size;
  hipLaunchKernelGGL(fps_kernel, dim3(B_), dim3(THREADS_), 0, stream, x, out);
}

// Round 11
// 6021.247 us; speedup vs baseline: 1.4186x; 1.4186x over previous
//
#include <hip/hip_runtime.h>
#include <cstdint>

// Reference semantics (validated, absmax=0.0 — DO NOT change arithmetic):
//  - selection on RAW f32 coords, distance = fma(dz,dz, fma(dx,dx, dy*dy))
//    with dx/dy/dz plain f32 subs;
//  - min/argmax exact, FIRST-index tie-break (min global point index);
//  - output coords bf16-RNE-rounded, batch = float b.
//
// R22: allocator's VGPR budget tracks BLOCK SIZE only (1024thr -> 52 regs
// across R12-R21 regardless of LDS/attrs; 512thr -> 84 in R11). So move to
// 512 threads x 32 points where the budget fits the live set:
//   x,y in LDS (s_xy[16384] float2, 128 KB, 1 block/CU), z+m in 64 named
//   regs + ~16 temps ~= 80 <= 84 budget -> no remat, no spill.
// Bonus: per-thread overhead (reduce/finalize/loop) amortizes over 2x
// points -> per-CU issue drops ~18%; half the waves -> half the barrier
// skew; block finalize is 3 DPP levels (8 keys) not 4 (16).
// Everything else is a pure transplant of validated R19: same bit-exact
// UPD, same DPP wave argmax, same u64-key parity-double-buffered exchange,
// single barrier per iteration, center = s_xy LDS + global z.
#pragma clang fp contract(off)

#define B_ 16
#define N_ 16384
#define K_ 4096
#define THREADS_ 512
#define PTS_ (N_ / THREADS_)   // 32 points per thread
#define NW_ (THREADS_ / 64)    // 8 waves per block

#define PTS_LIST(X) \
  X(0) X(1) X(2) X(3) X(4) X(5) X(6) X(7) \
  X(8) X(9) X(10) X(11) X(12) X(13) X(14) X(15) \
  X(16) X(17) X(18) X(19) X(20) X(21) X(22) X(23) \
  X(24) X(25) X(26) X(27) X(28) X(29) X(30) X(31)

// f32 -> bf16 RNE, returned as the bf16-representable f32 (finite inputs)
__device__ __forceinline__ float bfr(float f) {
  union { float f; uint32_t i; } c; c.f = f;
  c.i = (c.i + 0x7FFFu + ((c.i >> 16) & 1u)) & 0xFFFF0000u;
  return c.f;
}

// ---- DPP helpers (ctrl is a template constant) -----------------------------
template <int CTRL>
__device__ __forceinline__ float dpp_fmax(float v) {
  union { float f; int i; } s, p;
  s.f = v;
  p.i = __builtin_amdgcn_update_dpp(0, s.i, CTRL, 0xF, 0xF, false);
  return fmaxf(v, p.f);
}
template <int CTRL>
__device__ __forceinline__ unsigned dpp_umin(unsigned v) {
  const int p = __builtin_amdgcn_update_dpp((int)0xFFFFFFFFu, (int)v,
                                            CTRL, 0xF, 0xF, false);
  const unsigned pu = (unsigned)p;
  return pu < v ? pu : v;
}

// wave-wide (max bv, min bg among maxed) -> (wv, wg), uniform in all lanes.
__device__ __forceinline__ void wave_argmax(float bv, unsigned bg,
                                            float& wv, unsigned& wg) {
  float v = bv;
  v = dpp_fmax<0x111>(v);  // row_shr:1
  v = dpp_fmax<0x112>(v);  // row_shr:2
  v = dpp_fmax<0x114>(v);  // row_shr:4
  v = dpp_fmax<0x118>(v);  // row_shr:8
  v = dpp_fmax<0x142>(v);  // row_bcast:15
  v = dpp_fmax<0x143>(v);  // row_bcast:31
  union { float f; int i; } mx;
  mx.i = __builtin_amdgcn_readlane(__builtin_bit_cast(int, v), 63);
  unsigned c = (bv == mx.f) ? bg : 0xFFFFFFFFu;
  c = dpp_umin<0x111>(c);
  c = dpp_umin<0x112>(c);
  c = dpp_umin<0x114>(c);
  c = dpp_umin<0x118>(c);
  c = dpp_umin<0x142>(c);
  c = dpp_umin<0x143>(c);
  wg = (unsigned)__builtin_amdgcn_readlane((int)c, 63);
  wv = mx.f;
}

// u64 key max over a DPP lane-permutation (block-finalize butterfly; key is
// (f32bits(dist)<<32)|~idx so u64 max == (max dist, min index)). Exact.
template <int CTRL>
__device__ __forceinline__ unsigned long long kmax_dpp(unsigned long long k) {
  const int lo = (int)(unsigned)k;
  const int hi = (int)(unsigned)(k >> 32);
  const int plo = __builtin_amdgcn_update_dpp(lo, lo, CTRL, 0xF, 0xF, true);
  const int phi = __builtin_amdgcn_update_dpp(hi, hi, CTRL, 0xF, 0xF, true);
  const unsigned long long ok =
      ((unsigned long long)(unsigned)phi << 32) | (unsigned)plo;
  return ok > k ? ok : k;
}

__global__ __attribute__((amdgpu_flat_work_group_size(THREADS_, THREADS_),
                          amdgpu_waves_per_eu(1, 2)))
void fps_kernel(const float* __restrict__ x, float* __restrict__ out)
{
#pragma clang fp contract(off)
  const int b    = blockIdx.x;
  const int t    = threadIdx.x;
  const int lane = t & 63;
  const int wave = t >> 6;

  // x,y of all 16384 points (128 KB -> 1 block/CU). Slot i of thread t is
  // point i*512+t: per-iter reads are ds_read_b64 at base + i*4096B; center
  // reads are uniform-address broadcasts. Written once at init.
  __shared__ float2 s_xy[N_];
  // parity-double-buffered per-wave argmax keys: one barrier per iteration
  __shared__ unsigned long long s_key[2][NW_];

  const float* xb  = x + (size_t)b * (N_ * 3);
  float* out_x     = out;                        // [B*K*3] f32 (bf16-grid values)
  float* out_batch = out + (size_t)B_ * K_ * 3;  // [B*K]   f32 cloud ids

  // batch output (buffer re-poisoned every call -> rewrite every call)
  {
    const float bb = (float)b;
    for (int i = t; i < K_; i += THREADS_) out_batch[b * K_ + i] = bb;
  }

  // z and running-min in named registers; x,y staged to LDS
#define DECLP(i) float pz##i, m##i;
  PTS_LIST(DECLP)
#undef DECLP

#define LOADP(i) { const float* p_ = xb + 3 * ((i) * THREADS_ + t); \
                   float2 v_; v_.x = p_[0]; v_.y = p_[1];           \
                   s_xy[(i) * THREADS_ + t] = v_;                   \
                   pz##i = p_[2]; m##i = __builtin_inff(); }
  PTS_LIST(LOADP)
#undef LOADP

  // dist update (bit-exact FMA-V1), min into m##i; x,y from LDS (same bits)
#define UPD(i) { const float2 v_ = s_xy[(i) * THREADS_ + t];                    \
                 const float dx_ = v_.x - cx;                                   \
                 const float dy_ = v_.y - cy;                                   \
                 const float dz_ = pz##i - cz;                                  \
                 const float d_  = __builtin_fmaf(dz_, dz_,                     \
                                   __builtin_fmaf(dx_, dx_, dy_ * dy_));        \
                 m##i = fminf(m##i, d_); }

  // max3 tree over the 32 m values; value identical to sequential max.
#define MAXTREE(M_) {                                                       \
      const float t0_ = fmaxf(fmaxf(m0,  m1),  m2);                         \
      const float t1_ = fmaxf(fmaxf(m3,  m4),  m5);                         \
      const float t2_ = fmaxf(fmaxf(m6,  m7),  m8);                         \
      const float t3_ = fmaxf(fmaxf(m9,  m10), m11);                        \
      const float t4_ = fmaxf(fmaxf(m12, m13), m14);                        \
      const float t5_ = fmaxf(fmaxf(m15, m16), m17);                        \
      const float t6_ = fmaxf(fmaxf(m18, m19), m20);                        \
      const float t7_ = fmaxf(fmaxf(m21, m22), m23);                        \
      const float t8_ = fmaxf(fmaxf(m24, m25), m26);                        \
      const float t9_ = fmaxf(fmaxf(m27, m28), m29);                        \
      const float u0_ = fmaxf(fmaxf(t0_, t1_), t2_);                        \
      const float u1_ = fmaxf(fmaxf(t3_, t4_), t5_);                        \
      const float u2_ = fmaxf(fmaxf(t6_, t7_), t8_);                        \
      const float u3_ = fmaxf(fmaxf(t9_, m30), m31);                        \
      M_ = fmaxf(fmaxf(u0_, u1_), fmaxf(u2_, u3_)); }

  // descending equality chain: final bs = smallest slot with m==M
#define IDXCHAIN(M_, BS_) { BS_ = 31;                                \
      if (m30 == M_) BS_ = 30; if (m29 == M_) BS_ = 29;              \
      if (m28 == M_) BS_ = 28; if (m27 == M_) BS_ = 27;              \
      if (m26 == M_) BS_ = 26; if (m25 == M_) BS_ = 25;              \
      if (m24 == M_) BS_ = 24; if (m23 == M_) BS_ = 23;              \
      if (m22 == M_) BS_ = 22; if (m21 == M_) BS_ = 21;              \
      if (m20 == M_) BS_ = 20; if (m19 == M_) BS_ = 19;              \
      if (m18 == M_) BS_ = 18; if (m17 == M_) BS_ = 17;              \
      if (m16 == M_) BS_ = 16; if (m15 == M_) BS_ = 15;              \
      if (m14 == M_) BS_ = 14; if (m13 == M_) BS_ = 13;              \
      if (m12 == M_) BS_ = 12; if (m11 == M_) BS_ = 11;              \
      if (m10 == M_) BS_ = 10; if (m9  == M_) BS_ = 9;               \
      if (m8  == M_) BS_ = 8;  if (m7  == M_) BS_ = 7;               \
      if (m6  == M_) BS_ = 6;  if (m5  == M_) BS_ = 5;               \
      if (m4  == M_) BS_ = 4;  if (m3  == M_) BS_ = 3;               \
      if (m2  == M_) BS_ = 2;  if (m1  == M_) BS_ = 1;               \
      if (m0  == M_) BS_ = 0; }

  // per-thread argmax -> wave argmax -> per-wave key in LDS
#define REDUCE_AND_POST(PARITY) {                                        \
      float bv; int bs;                                                  \
      MAXTREE(bv)                                                        \
      IDXCHAIN(bv, bs)                                                   \
      const unsigned bg = (unsigned)(bs * THREADS_ + t);                 \
      float wv; unsigned wg;                                             \
      wave_argmax(bv, bg, wv, wg);                                       \
      if (lane == 0) {                                                   \
        union { float f; unsigned u; } cv; cv.f = wv;                    \
        s_key[PARITY][wave] =                                            \
            ((unsigned long long)cv.u << 32) | (unsigned)~wg;            \
      } }

  // ---- iteration 0: seed = point 0 ----
  float cx = xb[0], cy = xb[1], cz = xb[2];
  if (t == 0) {
    const uint64_t o = ((uint64_t)b * K_) * 3;
    out_x[o + 0] = bfr(cx); out_x[o + 1] = bfr(cy); out_x[o + 2] = bfr(cz);
  }

  PTS_LIST(UPD)                      // m_i = d_i (min with +inf)
  REDUCE_AND_POST(0)
  __syncthreads();

  // ---- iterations 1..K-1 ----
  for (int j = 1; j < K_; ++j) {
    const int rp = (j - 1) & 1;
    const int wp = j & 1;

    // finalize block argmax: 8 per-wave keys broadcast (lane&7), 3 DPP
    // levels within each 8-lane group -> every lane holds the block winner.
    unsigned long long k = s_key[rp][lane & 7];
    k = kmax_dpp<0xB1>(k);    // quad_perm lane^1
    k = kmax_dpp<0x4E>(k);    // quad_perm lane^2
    k = kmax_dpp<0x141>(k);   // row_half_mirror (lane^7, covers ^4)
    const unsigned idx = ~(unsigned)k;           // winner global point index
    const int gu = __builtin_amdgcn_readfirstlane((int)idx);

    // center: x,y from LDS (uniform broadcast read), z from global (L2;
    // latency hides under the cz-independent xy VALU below)
    const float2 cxy = s_xy[gu];
    cx = cxy.x; cy = cxy.y;
    cz = xb[3 * gu + 2];
    if (t == 0) {
      const uint64_t o = ((uint64_t)b * K_ + j) * 3;
      out_x[o + 0] = bfr(cx); out_x[o + 1] = bfr(cy); out_x[o + 2] = bfr(cz);
    }

    // update mind + per-thread/wave argmax for next round
    PTS_LIST(UPD)
    REDUCE_AND_POST(wp)
    __syncthreads();
  }
#undef UPD
#undef MAXTREE
#undef IDXCHAIN
#undef REDUCE_AND_POST

}

extern "C" void kernel_launch(void* const* d_in, const int* in_sizes, int n_in,
                              void* d_out, int out_size, void* d_ws, size_t ws_size,
                              hipStream_t stream) {
  const float* x = (const float*)d_in[0];  // f32, [B*N, 3]
  float* out     = (float*)d_out;          // f32: [B*K*3] coords + [B*K] batch
  (void)in_sizes; (void)n_in; (void)out_size; (void)d_ws; (void)ws_size;
  hipLaunchKernelGGL(fps_kernel, dim3(B_), dim3(THREADS_), 0, stream, x, out);
}